// Round 6
// baseline (471.048 us; speedup 1.0000x reference)
//
#include <hip/hip_runtime.h>
#include <hip/hip_bf16.h>

typedef short bf16x8 __attribute__((ext_vector_type(8)));
typedef float f32x4 __attribute__((ext_vector_type(4)));
typedef unsigned int u32x4 __attribute__((ext_vector_type(4)));

__device__ __forceinline__ unsigned short f2bf(float f) {
    unsigned int u = __float_as_uint(f);
    unsigned int r = u + 0x7fffu + ((u >> 16) & 1u);
    return (unsigned short)(r >> 16);
}
__device__ __forceinline__ float bf2f(unsigned short b) {
    return __uint_as_float(((unsigned int)b) << 16);
}
__device__ __forceinline__ unsigned int packbf2(float lo, float hi) {
    return ((unsigned int)f2bf(hi) << 16) | (unsigned int)f2bf(lo);
}

// ---------------- generic per-block bucket histogram (bucket = key>>8) ----------------
__global__ __launch_bounds__(256) void histk_k(const int* __restrict__ key, int* __restrict__ hist,
                                               int e, int nbuk, int nblk, int eb) {
    __shared__ int lh[512];
    int blk = blockIdx.x, t = threadIdx.x;
    for (int j = t; j < nbuk; j += 256) lh[j] = 0;
    __syncthreads();
    int e0 = blk * eb, e1 = min(e, e0 + eb);
    for (int i = e0 + t; i < e1; i += 256) atomicAdd(&lh[key[i] >> 8], 1);
    __syncthreads();
    for (int j = t; j < nbuk; j += 256) hist[(size_t)j * nblk + blk] = lh[j];
}

// ---------------- per-bucket exclusive scan over blocks; bucket totals ----------------
__global__ __launch_bounds__(256) void scanA_k(int* __restrict__ hist, int* __restrict__ btot, int nbuk, int nblk) {
    int w = (blockIdx.x * 256 + threadIdx.x) >> 6;
    int lane = threadIdx.x & 63;
    if (w >= nbuk) return;
    size_t base = (size_t)w * nblk;
    int run = 0;
    for (int c = 0; c < nblk; c += 64) {
        int i = c + lane;
        int v = (i < nblk) ? hist[base + i] : 0;
        int orig = v;
        for (int d = 1; d < 64; d <<= 1) { int u = __shfl_up(v, d); if (lane >= d) v += u; }
        if (i < nblk) hist[base + i] = run + v - orig;   // exclusive within bucket
        run += __shfl(v, 63);
    }
    if (lane == 0) btot[w] = run;
}

// ---------------- scan bucket totals -> bucket bases ----------------
__global__ __launch_bounds__(512) void scanB_k(const int* __restrict__ btot, int* __restrict__ bbase, int nbuk) {
    __shared__ int s[512];
    int t = threadIdx.x;
    int v = (t < nbuk) ? btot[t] : 0;
    s[t] = v;
    __syncthreads();
    for (int st = 1; st < 512; st <<= 1) {
        int add = (t >= st) ? s[t - st] : 0;
        __syncthreads();
        s[t] += add;
        __syncthreads();
    }
    if (t < nbuk) bbase[t] = s[t] - v;
    if (t == nbuk - 1) bbase[nbuk] = s[t];
}

// ---------------- sort pass 1: scatter (src,dst) into src-bucket regions ----------------
__global__ __launch_bounds__(256) void scatter1_k(const int* __restrict__ src, const int* __restrict__ dst,
                                                  const int* __restrict__ hist, const int* __restrict__ bbase,
                                                  int* __restrict__ es_s, int* __restrict__ es_d,
                                                  int e, int nbuk, int nblk, int eb) {
    __shared__ int cur[512];
    int blk = blockIdx.x, t = threadIdx.x;
    for (int j = t; j < nbuk; j += 256) cur[j] = bbase[j] + hist[(size_t)j * nblk + blk];
    __syncthreads();
    int e0 = blk * eb, e1 = min(e, e0 + eb);
    for (int i = e0 + t; i < e1; i += 256) {
        int s = src[i], d = dst[i];
        int p = atomicAdd(&cur[s >> 8], 1);
        es_s[p] = s;
        es_d[p] = d;
    }
}

// ---------------- sort pass 2: scatter src-sorted edges into dst-bucket regions ----------------
__global__ __launch_bounds__(256) void scatter2_k(const int* __restrict__ es_s, const int* __restrict__ es_d,
                                                  const int* __restrict__ hist, const int* __restrict__ bbase,
                                                  unsigned int* __restrict__ coarse,
                                                  int e, int nbuk, int nblk, int eb) {
    __shared__ int cur[512];
    int blk = blockIdx.x, t = threadIdx.x;
    for (int j = t; j < nbuk; j += 256) cur[j] = bbase[j] + hist[(size_t)j * nblk + blk];
    __syncthreads();
    int e0 = blk * eb, e1 = min(e, e0 + eb);
    for (int i = e0 + t; i < e1; i += 256) {
        int s = es_s[i], d = es_d[i];
        int p = atomicAdd(&cur[d >> 8], 1);
        coarse[p] = ((unsigned int)(d & 255) << 24) | (unsigned int)s;
    }
}

// ---------------- fine sort within dst bucket -> row_ptr, col, dis ----------------
__global__ __launch_bounds__(256) void bucket_k(const unsigned int* __restrict__ coarse, const int* __restrict__ bbase,
                                                float* __restrict__ dis, int* __restrict__ row_ptr, int* __restrict__ col,
                                                int n, int nbuk, int e) {
    __shared__ int h[256];
    __shared__ int s[256];
    __shared__ int cur[256];
    int b = blockIdx.x, t = threadIdx.x;
    int e0 = bbase[b], e1 = bbase[b + 1];
    h[t] = 0;
    __syncthreads();
    for (int i = e0 + t; i < e1; i += 256) atomicAdd(&h[coarse[i] >> 24], 1);
    __syncthreads();
    int v = h[t];
    s[t] = v;
    __syncthreads();
    for (int st = 1; st < 256; st <<= 1) {
        int add = (t >= st) ? s[t - st] : 0;
        __syncthreads();
        s[t] += add;
        __syncthreads();
    }
    int excl = s[t] - v;
    int node = b * 256 + t;
    if (node < n) {
        row_ptr[node] = e0 + excl;
        dis[node] = rsqrtf((float)v + 1.0f);
    }
    cur[t] = e0 + excl;
    __syncthreads();
    for (int i = e0 + t; i < e1; i += 256) {
        unsigned int pk = coarse[i];
        int p = atomicAdd(&cur[pk >> 24], 1);
        col[p] = (int)(pk & 0x00FFFFFFu);
    }
    if (b == nbuk - 1 && t == 0) row_ptr[n] = e;
}

// ---------------- MFMA GEMM: C[r] = dis[r] * (A[r] @ W); A f32 (layer1) or bf16; C bf16 ----------------
template <bool INF32>
__global__ __launch_bounds__(256) void gemm_mfma_k(const void* __restrict__ Av, const float* __restrict__ W,
                                                   const float* __restrict__ dis, unsigned short* __restrict__ C,
                                                   int nrows) {
    __shared__ unsigned short WT[128 * 136];   // W^T[n][k], pad ld=136 to dodge bank conflicts
    int t = threadIdx.x;
    for (int i = t; i < 16384; i += 256) {
        int k = i >> 7, nn = i & 127;
        WT[nn * 136 + k] = f2bf(W[i]);
    }
    __syncthreads();
    int wave = t >> 6, lane = t & 63;
    int lm = lane & 15, lg = lane >> 4;      // lg in 0..3
    for (int m0 = blockIdx.x * 64; m0 < nrows; m0 += gridDim.x * 64) {
        int R = m0 + wave * 16;
        int arow = R + lm;
        if (arow >= nrows) arow = nrows - 1;
        f32x4 acc[8];
#pragma unroll
        for (int q = 0; q < 8; q++) acc[q] = (f32x4){0.f, 0.f, 0.f, 0.f};
#pragma unroll
        for (int kk = 0; kk < 4; kk++) {
            bf16x8 af;
            if constexpr (INF32) {
                const float4* ap = (const float4*)((const float*)Av + (size_t)arow * 128 + kk * 32 + lg * 8);
                float4 a0 = ap[0], a1 = ap[1];
                u32x4 au;
                au[0] = packbf2(a0.x, a0.y); au[1] = packbf2(a0.z, a0.w);
                au[2] = packbf2(a1.x, a1.y); au[3] = packbf2(a1.z, a1.w);
                af = __builtin_bit_cast(bf16x8, au);
            } else {
                const u32x4* ap = (const u32x4*)((const unsigned short*)Av + (size_t)arow * 128);
                af = __builtin_bit_cast(bf16x8, ap[kk * 4 + lg]);
            }
#pragma unroll
            for (int q = 0; q < 8; q++) {
                const u32x4* bp = (const u32x4*)(WT + (q * 16 + lm) * 136 + kk * 32 + lg * 8);
                bf16x8 bfr = __builtin_bit_cast(bf16x8, *bp);          // B[k][n=q*16+lm]
                acc[q] = __builtin_amdgcn_mfma_f32_16x16x32_bf16(af, bfr, acc[q], 0, 0, 0);
            }
        }
        float dsc[4];
#pragma unroll
        for (int i2 = 0; i2 < 4; i2++) {
            int r = R + lg * 4 + i2;
            dsc[i2] = (r < nrows) ? dis[r] : 0.f;
        }
#pragma unroll
        for (int i2 = 0; i2 < 4; i2++) {
            int r = R + lg * 4 + i2;
            if (r < nrows) {
                unsigned short* cp = C + (size_t)r * 128 + lm;
#pragma unroll
                for (int q = 0; q < 8; q++) cp[q * 16] = f2bf(acc[q][i2] * dsc[i2]);
            }
        }
    }
}

// ---------------- aggregation: out[n] = relu(b + dis[n]*(h'[n] + sum h'[col[e]]))
// wave = 1 node; 4 edge-streams x 16 lanes; each lane gathers 16 B; 4-deep unroll per stream
__global__ __launch_bounds__(256) void agg_k(const unsigned short* __restrict__ h, unsigned short* __restrict__ out,
                                             const int* __restrict__ row_ptr, const int* __restrict__ col,
                                             const float* __restrict__ dis, const float* __restrict__ bias, int n) {
    int wid  = (blockIdx.x * 256 + threadIdx.x) >> 6;
    int lane = threadIdx.x & 63;
    if (wid >= n) return;
    int g = lane >> 4;                 // edge stream 0..3
    int s = lane & 15;                 // 16B chunk within 256B row
    const char* hb = (const char*)h;
    unsigned int soff = (unsigned int)(s << 4);
    float acc0 = 0.f, acc1 = 0.f, acc2 = 0.f, acc3 = 0.f;
    float acc4 = 0.f, acc5 = 0.f, acc6 = 0.f, acc7 = 0.f;
#define ACCUM(v)                                                                              \
    acc0 += __uint_as_float((v)[0] << 16); acc1 += __uint_as_float((v)[0] & 0xffff0000u);     \
    acc2 += __uint_as_float((v)[1] << 16); acc3 += __uint_as_float((v)[1] & 0xffff0000u);     \
    acc4 += __uint_as_float((v)[2] << 16); acc5 += __uint_as_float((v)[2] & 0xffff0000u);     \
    acc6 += __uint_as_float((v)[3] << 16); acc7 += __uint_as_float((v)[3] & 0xffff0000u);
    if (g == 0) {   // self-loop row
        u32x4 v = *(const u32x4*)(hb + (((unsigned int)wid << 8) + soff));
        ACCUM(v)
    }
    int e = row_ptr[wid] + g, e1 = row_ptr[wid + 1];
    // main loop: 4 edges per stream in flight (16 rows / 4 KB per wave)
    for (; e + 12 < e1; e += 16) {
        int c0 = col[e], c1 = col[e + 4], c2 = col[e + 8], c3 = col[e + 12];
        u32x4 v0 = *(const u32x4*)(hb + (((unsigned int)c0 << 8) + soff));
        u32x4 v1 = *(const u32x4*)(hb + (((unsigned int)c1 << 8) + soff));
        u32x4 v2 = *(const u32x4*)(hb + (((unsigned int)c2 << 8) + soff));
        u32x4 v3 = *(const u32x4*)(hb + (((unsigned int)c3 << 8) + soff));
        ACCUM(v0)
        ACCUM(v1)
        ACCUM(v2)
        ACCUM(v3)
    }
    for (; e < e1; e += 4) {
        u32x4 v = *(const u32x4*)(hb + (((unsigned int)col[e] << 8) + soff));
        ACCUM(v)
    }
#undef ACCUM
    // combine the 4 edge-streams (lane bits 4,5)
#define RED(a) a += __shfl_xor(a, 16); a += __shfl_xor(a, 32);
    RED(acc0) RED(acc1) RED(acc2) RED(acc3) RED(acc4) RED(acc5) RED(acc6) RED(acc7)
#undef RED
    if (g == 0) {
        float d = dis[wid];
        const float4* bp = (const float4*)bias;
        float4 ba = bp[2 * s], bb = bp[2 * s + 1];
        u32x4 r;
        r[0] = packbf2(fmaxf(ba.x + d * acc0, 0.f), fmaxf(ba.y + d * acc1, 0.f));
        r[1] = packbf2(fmaxf(ba.z + d * acc2, 0.f), fmaxf(ba.w + d * acc3, 0.f));
        r[2] = packbf2(fmaxf(bb.x + d * acc4, 0.f), fmaxf(bb.y + d * acc5, 0.f));
        r[3] = packbf2(fmaxf(bb.z + d * acc6, 0.f), fmaxf(bb.w + d * acc7, 0.f));
        *(u32x4*)((char*)out + (((unsigned int)wid << 8) + soff)) = r;
    }
}

// ---------------- fused global mean pool + classifier ----------------
__global__ __launch_bounds__(128) void pool_logits_k(const unsigned short* __restrict__ h, const int* __restrict__ batch,
                                                     const float* __restrict__ Wc, const float* __restrict__ bc,
                                                     float* __restrict__ logits, float* __restrict__ pooled,
                                                     int n, int nc) {
    __shared__ float pl[128];
    int g = blockIdx.x;
    int j = threadIdx.x;
    int lo = 0, hi = n;
    while (lo < hi) { int mid = (lo + hi) >> 1; if (batch[mid] < g) lo = mid + 1; else hi = mid; }
    int start = lo;
    hi = n;
    while (lo < hi) { int mid = (lo + hi) >> 1; if (batch[mid] < g + 1) lo = mid + 1; else hi = mid; }
    int end = lo;
    float acc = 0.f;
    for (int r = start; r < end; r++) acc += bf2f(h[(size_t)r * 128 + j]);
    float pv = acc / fmaxf((float)(end - start), 1.0f);
    pooled[(size_t)g * 128 + j] = pv;
    pl[j] = pv;
    __syncthreads();
    if (j < nc) {
        float a = bc[j];
#pragma unroll 8
        for (int k = 0; k < 128; k++) a += pl[k] * Wc[k * nc + j];
        logits[(size_t)g * nc + j] = a;
    }
}

extern "C" void kernel_launch(void* const* d_in, const int* in_sizes, int n_in,
                              void* d_out, int out_size, void* d_ws, size_t ws_size,
                              hipStream_t stream) {
    const float* x     = (const float*)d_in[0];
    const int*   ei    = (const int*)d_in[1];
    const int*   batch = (const int*)d_in[2];
    const float* W1    = (const float*)d_in[3];
    const float* b1    = (const float*)d_in[4];
    const float* W2    = (const float*)d_in[5];
    const float* b2    = (const float*)d_in[6];
    const float* Wc    = (const float*)d_in[7];
    const float* bc    = (const float*)d_in[8];
    float* out = (float*)d_out;

    const int N = in_sizes[0] / 128;
    const int E = in_sizes[1] / 2;
    const int NC = 10;
    const int G = out_size / (NC + 128);

    const int* src = ei;
    const int* dst = ei + E;

    const int EB   = 16384;
    const int NBLK = (E + EB - 1) / EB;
    const int NBUK = (N + 255) / 256;

    // workspace carve (256B aligned)
    char* wbase = (char*)d_ws;
    size_t off = 0;
    auto alloc = [&](size_t bytes) -> void* {
        void* p = wbase + off;
        off = (off + bytes + 255) & ~(size_t)255;
        return p;
    };
    float* dis     = (float*)alloc((size_t)N * 4);
    int*   row_ptr = (int*)alloc((size_t)(N + 1) * 4);
    int*   hist1   = (int*)alloc((size_t)NBUK * NBLK * 4);
    int*   hist2   = (int*)alloc((size_t)NBUK * NBLK * 4);
    int*   btot    = (int*)alloc((size_t)NBUK * 4);
    int*   bbase1  = (int*)alloc((size_t)(NBUK + 1) * 4);
    int*   bbase2  = (int*)alloc((size_t)(NBUK + 1) * 4);
    int*   es_s    = (int*)alloc((size_t)E * 4);
    int*   es_d    = (int*)alloc((size_t)E * 4);
    unsigned int* coarse = (unsigned int*)alloc((size_t)E * 4);
    int*   col     = (int*)alloc((size_t)E * 4);
    unsigned short* bufT = (unsigned short*)alloc((size_t)N * 128 * 2);
    unsigned short* bufH = (unsigned short*)alloc((size_t)N * 128 * 2);

    // --- CSR build: stable two-pass counting sort (by src>>8, then by dst>>8, then fine dst) ---
    // pass A: sort edges by src bucket (gives gather locality in agg)
    histk_k<<<NBLK, 256, 0, stream>>>(src, hist1, E, NBUK, NBLK, EB);
    scanA_k<<<(NBUK * 64 + 255) / 256, 256, 0, stream>>>(hist1, btot, NBUK, NBLK);
    scanB_k<<<1, 512, 0, stream>>>(btot, bbase1, NBUK);
    scatter1_k<<<NBLK, 256, 0, stream>>>(src, dst, hist1, bbase1, es_s, es_d, E, NBUK, NBLK, EB);
    // pass B: stable sort by dst bucket (preserves src order within bucket)
    histk_k<<<NBLK, 256, 0, stream>>>(es_d, hist2, E, NBUK, NBLK, EB);
    scanA_k<<<(NBUK * 64 + 255) / 256, 256, 0, stream>>>(hist2, btot, NBUK, NBLK);
    scanB_k<<<1, 512, 0, stream>>>(btot, bbase2, NBUK);
    scatter2_k<<<NBLK, 256, 0, stream>>>(es_s, es_d, hist2, bbase2, coarse, E, NBUK, NBLK, EB);
    // fine sort within dst bucket
    bucket_k<<<NBUK, 256, 0, stream>>>(coarse, bbase2, dis, row_ptr, col, N, NBUK, E);

    gemm_mfma_k<true><<<512, 256, 0, stream>>>(x, W1, dis, bufT, N);
    agg_k<<<(N + 3) / 4, 256, 0, stream>>>(bufT, bufH, row_ptr, col, dis, b1, N);
    gemm_mfma_k<false><<<512, 256, 0, stream>>>(bufH, W2, dis, bufT, N);
    agg_k<<<(N + 3) / 4, 256, 0, stream>>>(bufT, bufH, row_ptr, col, dis, b2, N);

    float* pooled = out + (size_t)G * NC;
    pool_logits_k<<<G, 128, 0, stream>>>(bufH, batch, Wc, bc, out, pooled, N, NC);
}